// Round 11
// baseline (1992.983 us; speedup 1.0000x reference)
//
#include <hip/hip_runtime.h>
#include <hip/hip_bf16.h>
#include <math.h>

typedef float evf4 __attribute__((ext_vector_type(4)));
typedef float evf2 __attribute__((ext_vector_type(2)));

__device__ __forceinline__ void fma4(float4& a, float s, const float4& v) {
  a.x += s * v.x; a.y += s * v.y; a.z += s * v.z; a.w += s * v.w;
}
__device__ __forceinline__ float4 ntload4(const float4* p) {
  evf4 v = __builtin_nontemporal_load((const evf4*)p);
  return make_float4(v.x, v.y, v.z, v.w);
}
__device__ __forceinline__ float2 ntload2(const float2* p) {
  evf2 v = __builtin_nontemporal_load((const evf2*)p);
  return make_float2(v.x, v.y);
}

// ---------------- conv body: conv(3->32,k5,p2) + relu + maxpool2 -----------
__device__ __forceinline__ void conv_body(
    const float* __restrict__ pic, const float* __restrict__ cw,
    const float* __restrict__ cb, float* __restrict__ pooled,
    int bid, float tile[3][8][260]) {
  int php = bid & 63, ocg2 = (bid >> 6) & 1, b = bid >> 7;
  int tid = threadIdx.x;
  int pw = tid & 127, phl = tid >> 7;
  int ph = php * 2 + phl;
  int h_base = php * 4 - 2;
  for (int i = tid; i < 3 * 8 * 260; i += 256) {
    int c = i % 260; int rr = (i / 260) & 7; int ic = i / (260 * 8);
    int h = h_base + rr, w = c - 2;
    float v = 0.f;
    if (h >= 0 && h < 256 && w >= 0 && w < 256)
      v = pic[((size_t)b * 3 + ic) * 65536 + h * 256 + w];
    tile[ic][rr][c] = v;
  }
  __syncthreads();
  float acc[16][4];
#pragma unroll
  for (int o = 0; o < 16; ++o)
#pragma unroll
    for (int q = 0; q < 4; ++q) acc[o][q] = 0.f;
  int r0 = phl * 2;
  int c0 = pw * 2;
#pragma unroll
  for (int ic = 0; ic < 3; ++ic) {
    float win[6][6];
#pragma unroll
    for (int r = 0; r < 6; ++r)
#pragma unroll
      for (int cc = 0; cc < 6; ++cc) win[r][cc] = tile[ic][r0 + r][c0 + cc];
#pragma unroll
    for (int o = 0; o < 16; ++o) {
      const float* __restrict__ wk = cw + ((ocg2 * 16 + o) * 3 + ic) * 25;
#pragma unroll
      for (int kh = 0; kh < 5; ++kh)
#pragma unroll
        for (int kw = 0; kw < 5; ++kw) {
          float wv = wk[kh * 5 + kw];
          acc[o][0] += win[kh][kw] * wv;
          acc[o][1] += win[kh][kw + 1] * wv;
          acc[o][2] += win[kh + 1][kw] * wv;
          acc[o][3] += win[kh + 1][kw + 1] * wv;
        }
    }
  }
#pragma unroll
  for (int o = 0; o < 16; ++o) {
    float m = fmaxf(fmaxf(acc[o][0], acc[o][1]), fmaxf(acc[o][2], acc[o][3]));
    m = fmaxf(m + cb[ocg2 * 16 + o], 0.f);
    pooled[(((size_t)b * 32 + ocg2 * 16 + o) * 128 + ph) * 128 + pw] = m;
  }
}

__device__ __forceinline__ void wc_body(
    const float* __restrict__ w1, const float* __restrict__ w2,
    float* __restrict__ wc, int bx) {
  int i = bx * 256 + threadIdx.x;
  if (i >= 75 * 72) return;
  int r = i / 72, c = i - r * 72;
  float s = 0.f;
  for (int k = 0; k < 288; ++k) s += w1[r * 288 + k] * w2[k * 72 + c];
  wc[i] = s;
}

// ---- K1: conv (4096) + wc (22) ---------------------------------------------
__global__ __launch_bounds__(256) void k1_conv_wc_kernel(
    const float* __restrict__ pic, const float* __restrict__ cw,
    const float* __restrict__ cb, float* __restrict__ pooled,
    const float* __restrict__ gw, const float* __restrict__ gw2,
    float* __restrict__ wcb) {
  __shared__ float tile[3][8][260];
  int bid = blockIdx.x;
  if (bid < 4096) conv_body(pic, cw, cb, pooled, bid, tile);
  else            wc_body(gw, gw2, wcb, bid - 4096);
}

// ------- split-K GEMM body: X[32,K] @ W[K,N] -> partial[split][32][N] ------
// 2 cols/thread (float2 W loads, 8-deep register pipeline). Low VGPR (~116)
// so __launch_bounds__(256,4) gives 4 waves/SIMD = 4 blocks/CU.
// chunk % 128 == 0, X rows 16B-aligned.
__device__ __forceinline__ void gemm2c_body(
    const float* __restrict__ X, const float* __restrict__ W,
    float* __restrict__ partial, int K, int N, int chunk,
    int bx, int split, float xs[128][36]) {
  int tid = threadIdx.x;
  int colv = bx * 256 + tid;   // float2 column index
  int col0 = colv * 2;
  bool active = col0 < N;
  int k0 = split * chunk, k1 = min(k0 + chunk, K);
  size_t Nv = (size_t)(N >> 1);
  const float2* Wv = (const float2*)W;
  float2 acc[32];
#pragma unroll
  for (int b = 0; b < 32; ++b) acc[b] = make_float2(0.f, 0.f);

  auto fmablk = [&](int kk, const float2& w2) {
    const float4* xr = (const float4*)xs[kk];
#pragma unroll
    for (int b4 = 0; b4 < 8; ++b4) {
      float4 xv = xr[b4];
      acc[b4 * 4 + 0].x += xv.x * w2.x; acc[b4 * 4 + 0].y += xv.x * w2.y;
      acc[b4 * 4 + 1].x += xv.y * w2.x; acc[b4 * 4 + 1].y += xv.y * w2.y;
      acc[b4 * 4 + 2].x += xv.z * w2.x; acc[b4 * 4 + 2].y += xv.z * w2.y;
      acc[b4 * 4 + 3].x += xv.w * w2.x; acc[b4 * 4 + 3].y += xv.w * w2.y;
    }
  };

  for (int kt = k0; kt < k1; kt += 128) {
    __syncthreads();
#pragma unroll
    for (int j = 0; j < 4; ++j) {
      int idx = tid + j * 256;
      int b = idx >> 5, kk = (idx & 31) * 4;
      float4 x = *(const float4*)&X[(size_t)b * K + kt + kk];
      xs[kk + 0][b] = x.x; xs[kk + 1][b] = x.y;
      xs[kk + 2][b] = x.z; xs[kk + 3][b] = x.w;
    }
    __syncthreads();
    if (active) {
      const float2* wp = Wv + (size_t)kt * Nv + colv;
      float2 cur[8], nxt[8];
#pragma unroll
      for (int j = 0; j < 8; ++j) cur[j] = ntload2(wp + (size_t)j * Nv);
#pragma unroll 1
      for (int g = 0; g < 15; ++g) {
        const float2* wn = wp + 8 * Nv;
#pragma unroll
        for (int j = 0; j < 8; ++j) nxt[j] = ntload2(wn + (size_t)j * Nv);
        int kb = g * 8;
#pragma unroll
        for (int j = 0; j < 8; ++j) fmablk(kb + j, cur[j]);
#pragma unroll
        for (int j = 0; j < 8; ++j) cur[j] = nxt[j];
        wp = wn;
      }
#pragma unroll
      for (int j = 0; j < 8; ++j) fmablk(120 + j, cur[j]);
    }
  }
  if (active) {
    float* p = partial + (size_t)split * 32 * N + col0;
#pragma unroll
    for (int b = 0; b < 32; ++b) *(float2*)(p + (size_t)b * N) = acc[b];
  }
}

// ---- K2: fc1 GEMM (512 blocks) + both mlp GEMMs (1008 blocks) --------------
__global__ __launch_bounds__(256, 4) void gemm_all_kernel(
    const float* __restrict__ pooled, const float* __restrict__ fc1w,
    float* __restrict__ pfc1,
    const float* __restrict__ rna, const float* __restrict__ m1w1, float* __restrict__ pm1,
    const float* __restrict__ cnv, const float* __restrict__ m2w1, float* __restrict__ pm2) {
  __shared__ float xs[128][36];
  int b = blockIdx.x;
  if (b < 512) {
    // fc1: chunk 2048, 256 splits x 2 col-blocks
    gemm2c_body(pooled, fc1w, pfc1, 524288, 1024, 2048, b & 1, b >> 1, xs);
  } else {
    int j = b - 512;          // 0..1007
    int z = j / 504;
    int r = j % 504;
    int bx = r & 7, split = r >> 3;   // split 0..62
    if (z == 0) gemm2c_body(rna, m1w1, pm1, 16000, 4000, 256, bx, split, xs);
    else        gemm2c_body(cnv, m2w1, pm2, 16000, 4000, 256, bx, split, xs);
  }
}

// ---- float4 reduce bodies ---------------------------------------------------
__device__ __forceinline__ void fadd4(float4& a, const float4& v) {
  a.x += v.x; a.y += v.y; a.z += v.z; a.w += v.w;
}

// fc1 stage1: sum 128 splits -> p2[sy][8192 f4]
__device__ __forceinline__ void reduce_s1_body(
    const float* __restrict__ partial, float* __restrict__ p2,
    int bx, int sy) {
  int i = bx * 256 + threadIdx.x;          // f4 index, 8192 per image
  const float4* p = (const float4*)partial + (size_t)(sy * 128) * 8192 + i;
  const size_t st = 8192;
  float4 s0 = make_float4(0, 0, 0, 0), s1 = s0, s2 = s0, s3 = s0;
  for (int sp = 0; sp < 128; sp += 4) {
    fadd4(s0, ntload4(p + (sp + 0) * st));
    fadd4(s1, ntload4(p + (sp + 1) * st));
    fadd4(s2, ntload4(p + (sp + 2) * st));
    fadd4(s3, ntload4(p + (sp + 3) * st));
  }
  float4 r;
  r.x = (s0.x + s1.x) + (s2.x + s3.x);
  r.y = (s0.y + s1.y) + (s2.y + s3.y);
  r.z = (s0.z + s1.z) + (s2.z + s3.z);
  r.w = (s0.w + s1.w) + (s2.w + s3.w);
  ((float4*)p2)[(size_t)sy * 8192 + i] = r;
}

// mlp reduce: nsplit=63, N=4000 (1000 f4/row, 32000 f4 total)
__device__ __forceinline__ void reduce_mlp_body(
    const float* __restrict__ partial, const float* __restrict__ bias,
    float* __restrict__ out, int bx) {
  int i = bx * 256 + threadIdx.x;
  if (i >= 32000) return;
  const float4* p = (const float4*)partial + i;
  const size_t st = 32000;
  float4 s0 = make_float4(0, 0, 0, 0), s1 = s0, s2 = s0, s3 = s0;
  int sp = 0;
  for (; sp + 4 <= 63; sp += 4) {
    fadd4(s0, ntload4(p + (sp + 0) * st));
    fadd4(s1, ntload4(p + (sp + 1) * st));
    fadd4(s2, ntload4(p + (sp + 2) * st));
    fadd4(s3, ntload4(p + (sp + 3) * st));
  }
  for (; sp < 63; ++sp) fadd4(s0, ntload4(p + (size_t)sp * st));
  float4 bi = ((const float4*)bias)[i % 1000];
  float4 r;
  r.x = fmaxf(bi.x + (s0.x + s1.x) + (s2.x + s3.x), 0.f);
  r.y = fmaxf(bi.y + (s0.y + s1.y) + (s2.y + s3.y), 0.f);
  r.z = fmaxf(bi.z + (s0.z + s1.z) + (s2.z + s3.z), 0.f);
  r.w = fmaxf(bi.w + (s0.w + s1.w) + (s2.w + s3.w), 0.f);
  ((float4*)out)[i] = r;
}

// ---- K3: fc1 reduce_s1 (64) + mlp reduces (250) -----------------------------
__global__ __launch_bounds__(256) void k3_reduce_kernel(
    const float* __restrict__ pfc1, float* __restrict__ p2fc1,
    const float* __restrict__ pm1, const float* __restrict__ m1b1, float* __restrict__ h1,
    const float* __restrict__ pm2, const float* __restrict__ m2b1, float* __restrict__ h2) {
  int b = blockIdx.x;
  if (b < 64) {
    reduce_s1_body(pfc1, p2fc1, b & 31, b >> 5);
  } else {
    int idx = b - 64;
    if (idx < 125) reduce_mlp_body(pm1, m1b1, h1, idx);
    else           reduce_mlp_body(pm2, m2b1, h2, idx - 125);
  }
}

// fc1 stage2: bias + 2 sy groups + relu (8192 f4)
__device__ __forceinline__ void reduce_s2_body(
    const float* __restrict__ p2, const float* __restrict__ bias,
    float* __restrict__ out, int bx) {
  int i = bx * 256 + threadIdx.x;
  float4 a = ((const float4*)p2)[i];
  float4 b = ((const float4*)p2)[8192 + i];
  float4 bi = ((const float4*)bias)[i & 255];
  float4 r;
  r.x = fmaxf(bi.x + a.x + b.x, 0.f);
  r.y = fmaxf(bi.y + a.y + b.y, 0.f);
  r.z = fmaxf(bi.z + a.z + b.z, 0.f);
  r.w = fmaxf(bi.w + a.w + b.w, 0.f);
  ((float4*)out)[i] = r;
}

// ------- per-drug GCN body: max(relu(Hn@(Hn@(X@Wc)))), 2x9 blocking --------
__device__ __forceinline__ void gcn_body(
    const float* __restrict__ Xg, const float* __restrict__ Ag,
    const float* __restrict__ Wc, float* __restrict__ drugfea, int d,
    float Hn[64][65], float Xs[64][75], float Wcs[75][72],
    float Ys[64][72], float Ts[64][72]) {
  int tid = threadIdx.x;
  const float* Ad = Ag + (size_t)d * 4096;
  const float* Xd = Xg + (size_t)d * 4800;
  for (int i = tid; i < 4096; i += 256) {
    int r = i & 63, c = i >> 6;
    Hn[r][c] = (r == c) ? 1.f : Ad[c * 64 + r];
  }
  for (int i = tid; i < 4800; i += 256) Xs[i / 75][i % 75] = Xd[i];
  for (int i = tid; i < 5400; i += 256) Wcs[i / 72][i % 72] = Wc[i];
  __syncthreads();
  if (tid < 64) {
    float s = 0.f;
    for (int c = 0; c < 64; ++c) s += Hn[tid][c];
    float inv = (s == 0.f) ? 0.f : 1.f / s;
    for (int c = 0; c < 64; ++c) Hn[tid][c] *= inv;
  }
  __syncthreads();
  int rb = tid >> 3, cb = tid & 7;
  int r0 = rb * 2, c0 = cb * 9;
  {
    float o0[9], o1[9];
#pragma unroll
    for (int j = 0; j < 9; ++j) { o0[j] = 0.f; o1[j] = 0.f; }
    for (int k = 0; k < 75; ++k) {
      float x0 = Xs[r0][k], x1 = Xs[r0 + 1][k];
#pragma unroll
      for (int j = 0; j < 9; ++j) {
        float w = Wcs[k][c0 + j];
        o0[j] += x0 * w; o1[j] += x1 * w;
      }
    }
#pragma unroll
    for (int j = 0; j < 9; ++j) { Ys[r0][c0 + j] = o0[j]; Ys[r0 + 1][c0 + j] = o1[j]; }
  }
  __syncthreads();
  {
    float o0[9], o1[9];
#pragma unroll
    for (int j = 0; j < 9; ++j) { o0[j] = 0.f; o1[j] = 0.f; }
    for (int k = 0; k < 64; ++k) {
      float x0 = Hn[r0][k], x1 = Hn[r0 + 1][k];
#pragma unroll
      for (int j = 0; j < 9; ++j) {
        float w = Ys[k][c0 + j];
        o0[j] += x0 * w; o1[j] += x1 * w;
      }
    }
#pragma unroll
    for (int j = 0; j < 9; ++j) { Ts[r0][c0 + j] = o0[j]; Ts[r0 + 1][c0 + j] = o1[j]; }
  }
  __syncthreads();
  {
    float o0[9], o1[9];
#pragma unroll
    for (int j = 0; j < 9; ++j) { o0[j] = 0.f; o1[j] = 0.f; }
    for (int k = 0; k < 64; ++k) {
      float x0 = Hn[r0][k], x1 = Hn[r0 + 1][k];
#pragma unroll
      for (int j = 0; j < 9; ++j) {
        float w = Ts[k][c0 + j];
        o0[j] += x0 * w; o1[j] += x1 * w;
      }
    }
#pragma unroll
    for (int j = 0; j < 9; ++j) {
      Ys[r0][c0 + j] = fmaxf(o0[j], 0.f);
      Ys[r0 + 1][c0 + j] = fmaxf(o1[j], 0.f);
    }
  }
  __syncthreads();
  if (tid < 72) {
    float m = Ys[0][tid];
    for (int i = 1; i < 64; ++i) m = fmaxf(m, Ys[i][tid]);
    drugfea[d * 72 + tid] = m;
  }
}

// ---- K4: fc1 reduce_s2 (32) + gcn (128) -------------------------------------
__global__ __launch_bounds__(256) void k4_s2_gcn_kernel(
    const float* __restrict__ p2fc1, const float* __restrict__ fc1_b,
    float* __restrict__ fcact,
    const float* __restrict__ Xg, const float* __restrict__ Ag,
    const float* __restrict__ wcb, float* __restrict__ drugfea) {
  __shared__ float Hn[64][65];
  __shared__ float Xs[64][75];
  __shared__ float Wcs[75][72];
  __shared__ float Ys[64][72];
  __shared__ float Ts[64][72];
  int b = blockIdx.x;
  if (b < 32) reduce_s2_body(p2fc1, fc1_b, fcact, b);
  else        gcn_body(Xg, Ag, wcb, drugfea, b - 32, Hn, Xs, Wcs, Ys, Ts);
}

// ------- x[32,K] @ W[K,36] + b, 3 branches fused, float4 W loads -----------
__global__ __launch_bounds__(256) void lin36_all_kernel(
    const float* __restrict__ X0, const float* __restrict__ W0,
    const float* __restrict__ bi0, float* __restrict__ out0,
    const float* __restrict__ X1, const float* __restrict__ W1,
    const float* __restrict__ bi1, float* __restrict__ out1,
    const float* __restrict__ X2, const float* __restrict__ W2,
    const float* __restrict__ bi2, float* __restrict__ out2) {
  const float* X; const float* W; const float* bias; float* out; int K; bool do_sm;
  if (blockIdx.y == 0)      { X = X0; W = W0; bias = bi0; out = out0; K = 4000; do_sm = true; }
  else if (blockIdx.y == 1) { X = X1; W = W1; bias = bi1; out = out1; K = 4000; do_sm = true; }
  else                      { X = X2; W = W2; bias = bi2; out = out2; K = 1024; do_sm = false; }
  __shared__ float xs[4000];
  __shared__ float red[28][36];
  __shared__ float vals[36];
  __shared__ float mxv, smv;
  int b = blockIdx.x, tid = threadIdx.x;
  for (int i = tid; i < K; i += 256) xs[i] = X[(size_t)b * K + i];
  __syncthreads();
  if (tid < 252) {
    int c4 = tid % 9, g = tid / 9;
    const float4* W4 = (const float4*)W;
    float4 s = make_float4(0.f, 0.f, 0.f, 0.f);
    for (int k = g; k < K; k += 28) fma4(s, xs[k], W4[k * 9 + c4]);
    red[g][c4 * 4 + 0] = s.x; red[g][c4 * 4 + 1] = s.y;
    red[g][c4 * 4 + 2] = s.z; red[g][c4 * 4 + 3] = s.w;
  }
  __syncthreads();
  if (tid < 36) {
    float s = bias[tid];
    for (int g = 0; g < 28; ++g) s += red[g][tid];
    vals[tid] = s;
  }
  __syncthreads();
  if (do_sm) {
    if (tid == 0) {
      float m = -1e30f;
      for (int j = 0; j < 36; ++j) m = fmaxf(m, vals[j]);
      float e = 0.f;
      for (int j = 0; j < 36; ++j) e += expf(vals[j] - m);
      mxv = m; smv = e;
    }
    __syncthreads();
    if (tid < 36) out[b * 36 + tid] = expf(vals[tid] - mxv) / smv;
  } else {
    if (tid < 36) out[b * 36 + tid] = vals[tid];
  }
}

// ---------------- attention + CLIP loss + cell_cat (single block) ----------
__global__ __launch_bounds__(256) void head_kernel(
    const float* __restrict__ rna1, const float* __restrict__ cnv1,
    const float* __restrict__ pic1r, const float* __restrict__ aw1,
    const float* __restrict__ ab1, const float* __restrict__ aw2,
    const float* __restrict__ scale_p, float* __restrict__ cell_cat,
    float* __restrict__ dout) {
  __shared__ float z[2][32][36];
  __shared__ float pic1n[32][36];
  __shared__ float celln[32][36];
  __shared__ float fea[32][32];
  __shared__ float wvp[64];
  __shared__ float beta0, beta1;
  __shared__ float rowl[32], coll[32];
  int tid = threadIdx.x;
  for (int i = tid; i < 1152; i += 256) {
    int b = i / 36, k = i - (i / 36) * 36;
    z[0][b][k] = rna1[i];
    z[1][b][k] = cnv1[i];
    pic1n[b][k] = pic1r[i];
  }
  __syncthreads();
  {
    int p = tid >> 2, sub = tid & 3;
    int b = p >> 1, v = p & 1;
    float s = 0.f;
    for (int h = sub; h < 128; h += 4) {
      float a = ab1[h];
      for (int k = 0; k < 36; ++k) a += z[v][b][k] * aw1[k * 128 + h];
      s += tanhf(a) * aw2[h];
    }
    s += __shfl_down(s, 1, 64);
    s += __shfl_down(s, 2, 64);
    if (sub == 0) wvp[p] = s;
  }
  __syncthreads();
  if (tid == 0) {
    float w0 = 0.f, w1 = 0.f;
    for (int b = 0; b < 32; ++b) { w0 += wvp[b * 2]; w1 += wvp[b * 2 + 1]; }
    w0 /= 32.f; w1 /= 32.f;
    float m = fmaxf(w0, w1);
    float e0 = expf(w0 - m), e1 = expf(w1 - m);
    beta0 = e0 / (e0 + e1); beta1 = e1 / (e0 + e1);
  }
  __syncthreads();
  for (int i = tid; i < 1152; i += 256) {
    int b = i / 36, k = i - (i / 36) * 36;
    celln[b][k] = beta0 * z[0][b][k] + beta1 * z[1][b][k];
  }
  __syncthreads();
  if (tid < 32) {
    float s = 0.f;
    for (int k = 0; k < 36; ++k) { float x = pic1n[tid][k]; s += x * x; }
    float inv = 1.f / sqrtf(s);
    for (int k = 0; k < 36; ++k) pic1n[tid][k] *= inv;
  } else if (tid < 64) {
    int b = tid - 32;
    float s = 0.f;
    for (int k = 0; k < 36; ++k) { float x = celln[b][k]; s += x * x; }
    float inv = 1.f / sqrtf(s);
    for (int k = 0; k < 36; ++k) celln[b][k] *= inv;
  }
  __syncthreads();
  for (int i = tid; i < 1152; i += 256) {
    int b = i / 36, k = i - (i / 36) * 36;
    cell_cat[b * 72 + k] = celln[b][k];
    cell_cat[b * 72 + 36 + k] = pic1n[b][k];
  }
  float sc = *scale_p;
  for (int t = tid; t < 1024; t += 256) {
    int i = t >> 5, j = t & 31;
    float s = 0.f;
    for (int k = 0; k < 36; ++k) s += pic1n[i][k] * celln[j][k];
    fea[i][j] = sc * s;
  }
  __syncthreads();
  if (tid < 32) {
    float m = -1e30f;
    for (int j = 0; j < 32; ++j) m = fmaxf(m, fea[tid][j]);
    float e = 0.f;
    for (int j = 0; j < 32; ++j) e += expf(fea[tid][j] - m);
    rowl[tid] = (logf(e) + m) - fea[tid][tid];
  } else if (tid < 64) {
    int j = tid - 32;
    float m = -1e30f;
    for (int i = 0; i < 32; ++i) m = fmaxf(m, fea[i][j]);
    float e = 0.f;
    for (int i = 0; i < 32; ++i) e += expf(fea[i][j] - m);
    coll[j] = (logf(e) + m) - fea[j][j];
  }
  __syncthreads();
  if (tid == 0) {
    float s1 = 0.f, s2 = 0.f;
    for (int i = 0; i < 32; ++i) { s1 += rowl[i]; s2 += coll[i]; }
    dout[1] = 0.5f * (s1 / 32.f + s2 / 32.f);
  }
}

// ---------------- pair head + per-block CE partial sums --------------------
__global__ __launch_bounds__(256) void pair_kernel(
    const float* __restrict__ cell_cat, const float* __restrict__ drugfea,
    const int* __restrict__ idx, const int* __restrict__ target,
    const float* __restrict__ w1, const float* __restrict__ b1,
    const float* __restrict__ w2, const float* __restrict__ b2,
    float* __restrict__ bp_out, float* __restrict__ tgt_out,
    float* __restrict__ blocksums) {
  __shared__ float w1s[144][36];
  __shared__ float ccs[32][73];
  __shared__ float dfs[128][73];
  __shared__ float w2s[72], b2s[2];
  __shared__ float lsum[256];
  int tid = threadIdx.x;
  {
    float4* dst = (float4*)&w1s[0][0];
    const float4* src = (const float4*)w1;
    for (int i = tid; i < 1296; i += 256) dst[i] = src[i];
  }
  for (int i = tid; i < 2304; i += 256) ccs[i / 72][i % 72] = cell_cat[i];
  for (int i = tid; i < 9216; i += 256) dfs[i / 72][i % 72] = drugfea[i];
  if (tid < 72) w2s[tid] = w2[tid];
  if (tid < 2) b2s[tid] = b2[tid];
  __syncthreads();
  int p = blockIdx.x * 256 + tid;
  int ci = idx[p * 2], dj = idx[p * 2 + 1];
  float4 h4[9];
  {
    const float4* bb = (const float4*)b1;
#pragma unroll
    for (int q = 0; q < 9; ++q) h4[q] = bb[q];
  }
  for (int k = 0; k < 72; ++k) {
    float x = ccs[ci][k];
    const float4* wr = (const float4*)&w1s[k][0];
#pragma unroll
    for (int q = 0; q < 9; ++q) fma4(h4[q], x, wr[q]);
  }
  for (int k = 0; k < 72; ++k) {
    float x = dfs[dj][k];
    const float4* wr = (const float4*)&w1s[72 + k][0];
#pragma unroll
    for (int q = 0; q < 9; ++q) fma4(h4[q], x, wr[q]);
  }
  float l0 = b2s[0], l1 = b2s[1];
#pragma unroll
  for (int q = 0; q < 9; ++q) {
    float hv;
    hv = fmaxf(h4[q].x, 0.f); l0 += hv * w2s[(q * 4 + 0) * 2]; l1 += hv * w2s[(q * 4 + 0) * 2 + 1];
    hv = fmaxf(h4[q].y, 0.f); l0 += hv * w2s[(q * 4 + 1) * 2]; l1 += hv * w2s[(q * 4 + 1) * 2 + 1];
    hv = fmaxf(h4[q].z, 0.f); l0 += hv * w2s[(q * 4 + 2) * 2]; l1 += hv * w2s[(q * 4 + 2) * 2 + 1];
    hv = fmaxf(h4[q].w, 0.f); l0 += hv * w2s[(q * 4 + 3) * 2]; l1 += hv * w2s[(q * 4 + 3) * 2 + 1];
  }
  float m = fmaxf(l0, l1);
  float e0 = expf(l0 - m), e1 = expf(l1 - m);
  float inv = 1.f / (e0 + e1);
  float p0 = e0 * inv, p1 = e1 * inv;
  bp_out[p * 2] = p0;
  bp_out[p * 2 + 1] = p1;
  int t = target[p];
  float mm = fmaxf(p0, p1);
  float lse = logf(expf(p0 - mm) + expf(p1 - mm)) + mm;
  float chosen = t ? p1 : p0;
  lsum[tid] = lse - chosen;
  tgt_out[p] = (float)t;
  __syncthreads();
  for (int s = 128; s > 0; s >>= 1) {
    if (tid < s) lsum[tid] += lsum[tid + s];
    __syncthreads();
  }
  if (tid == 0) blocksums[blockIdx.x] = lsum[0];
}

__global__ void final_kernel(const float* __restrict__ blocksums, float* __restrict__ dout) {
  if (threadIdx.x == 0 && blockIdx.x == 0) {
    float s = 0.f;
    for (int i = 0; i < 16; ++i) s += blocksums[i];
    dout[0] = s / 4096.f;
  }
}

extern "C" void kernel_launch(void* const* d_in, const int* in_sizes, int n_in,
                              void* d_out, int out_size, void* d_ws, size_t ws_size,
                              hipStream_t stream) {
  (void)in_sizes; (void)n_in; (void)out_size; (void)ws_size;
  const float* pic        = (const float*)d_in[0];
  const float* rna        = (const float*)d_in[1];
  const float* cnv        = (const float*)d_in[2];
  const float* drug_fea   = (const float*)d_in[3];
  const float* drug_adj   = (const float*)d_in[4];
  const int*   index_list = (const int*)d_in[5];
  const int*   target     = (const int*)d_in[6];
  const float* logit_scale= (const float*)d_in[7];
  const float* conv_w     = (const float*)d_in[8];
  const float* conv_b     = (const float*)d_in[9];
  const float* fc1_w      = (const float*)d_in[10];
  const float* fc1_b      = (const float*)d_in[11];
  const float* fc2_w      = (const float*)d_in[12];
  const float* fc2_b      = (const float*)d_in[13];
  const float* m1w1       = (const float*)d_in[14];
  const float* m1b1       = (const float*)d_in[15];
  const float* m1w2       = (const float*)d_in[16];
  const float* m1b2       = (const float*)d_in[17];
  const float* m2w1       = (const float*)d_in[18];
  const float* m2b1       = (const float*)d_in[19];
  const float* m2w2       = (const float*)d_in[20];
  const float* m2b2       = (const float*)d_in[21];
  const float* aw1        = (const float*)d_in[22];
  const float* ab1        = (const float*)d_in[23];
  const float* aw2        = (const float*)d_in[24];
  const float* ew1        = (const float*)d_in[25];
  const float* eb1        = (const float*)d_in[26];
  const float* ew2        = (const float*)d_in[27];
  const float* eb2        = (const float*)d_in[28];
  const float* gw         = (const float*)d_in[29];
  const float* gw2        = (const float*)d_in[30];

  float* ws = (float*)d_ws;
  float* pooled  = ws;                   // 16,777,216 f
  float* pfc1    = ws + 16777216;        //  8,388,608 f (256*32*1024)
  float* p2fc1   = ws + 33554432;        //     65,536 f (2*32*1024)
  float* pm1     = ws + 33685504;        //  8,064,000 f (63*32*4000)
  float* pm2     = ws + 41749504;        //  8,064,000 f
  float* fcact   = ws + 49813504;        //     32,768 f
  float* h1      = ws + 49846272;        //    128,000 f
  float* h2      = ws + 49974272;        //    128,000 f
  float* rna1    = ws + 50102272;        //      1,152 f
  float* cnv1    = ws + 50103424;
  float* pic1r   = ws + 50104576;
  float* wcb     = ws + 50105728;        //      5,400 f
  float* drugf   = ws + 50111128;        //      9,216 f
  float* cellcat = ws + 50120344;        //      2,304 f
  float* bsums   = ws + 50122648;        //         16 f

  float* out = (float*)d_out;

  // K1: conv (4096) + wc (22)
  k1_conv_wc_kernel<<<4118, 256, 0, stream>>>(pic, conv_w, conv_b, pooled,
                                              gw, gw2, wcb);
  // K2: fc1 GEMM (512) + mlp GEMMs (1008); 2 cols/thread, 4 blocks/CU
  gemm_all_kernel<<<1520, 256, 0, stream>>>(pooled, fc1_w, pfc1,
                                            rna, m1w1, pm1, cnv, m2w1, pm2);
  // K3: fc1 reduce stage1 (64) || mlp reduces (250), float4
  k3_reduce_kernel<<<314, 256, 0, stream>>>(pfc1, p2fc1,
                                            pm1, m1b1, h1, pm2, m2b1, h2);
  // K4: fc1 reduce stage2 (32) || drug GCN (128)
  k4_s2_gcn_kernel<<<160, 256, 0, stream>>>(p2fc1, fc1_b, fcact,
                                            drug_fea, drug_adj, wcb, drugf);
  // K5: the three 36-col linears (+softmax)
  {
    dim3 g(32, 3);
    lin36_all_kernel<<<g, 256, 0, stream>>>(h1, m1w2, m1b2, rna1,
                                            h2, m2w2, m2b2, cnv1,
                                            fcact, fc2_w, fc2_b, pic1r);
  }
  // K6: attention + CLIP loss
  head_kernel<<<1, 256, 0, stream>>>(rna1, cnv1, pic1r, aw1, ab1, aw2,
                                     logit_scale, cellcat, out);
  // K7: pair prediction head
  pair_kernel<<<16, 256, 0, stream>>>(cellcat, drugf, index_list, target,
                                      ew1, eb1, ew2, eb2,
                                      out + 2, out + 2 + 8192, bsums);
  // K8: final CE mean
  final_kernel<<<1, 64, 0, stream>>>(bsums, out);
}

// Round 12
// 1122.168 us; speedup vs baseline: 1.7760x; 1.7760x over previous
//
#include <hip/hip_runtime.h>
#include <hip/hip_bf16.h>
#include <math.h>

typedef float evf4 __attribute__((ext_vector_type(4)));
typedef float evf2 __attribute__((ext_vector_type(2)));

__device__ __forceinline__ void fma4(float4& a, float s, const float4& v) {
  a.x += s * v.x; a.y += s * v.y; a.z += s * v.z; a.w += s * v.w;
}
__device__ __forceinline__ float4 ntload4(const float4* p) {
  evf4 v = __builtin_nontemporal_load((const evf4*)p);
  return make_float4(v.x, v.y, v.z, v.w);
}
__device__ __forceinline__ float2 ntload2(const float2* p) {
  evf2 v = __builtin_nontemporal_load((const evf2*)p);
  return make_float2(v.x, v.y);
}

// ---------------- conv body: conv(3->32,k5,p2) + relu + maxpool2 -----------
__device__ __forceinline__ void conv_body(
    const float* __restrict__ pic, const float* __restrict__ cw,
    const float* __restrict__ cb, float* __restrict__ pooled,
    int bid, float tile[3][8][260]) {
  int php = bid & 63, ocg2 = (bid >> 6) & 1, b = bid >> 7;
  int tid = threadIdx.x;
  int pw = tid & 127, phl = tid >> 7;
  int ph = php * 2 + phl;
  int h_base = php * 4 - 2;
  for (int i = tid; i < 3 * 8 * 260; i += 256) {
    int c = i % 260; int rr = (i / 260) & 7; int ic = i / (260 * 8);
    int h = h_base + rr, w = c - 2;
    float v = 0.f;
    if (h >= 0 && h < 256 && w >= 0 && w < 256)
      v = pic[((size_t)b * 3 + ic) * 65536 + h * 256 + w];
    tile[ic][rr][c] = v;
  }
  __syncthreads();
  float acc[16][4];
#pragma unroll
  for (int o = 0; o < 16; ++o)
#pragma unroll
    for (int q = 0; q < 4; ++q) acc[o][q] = 0.f;
  int r0 = phl * 2;
  int c0 = pw * 2;
#pragma unroll
  for (int ic = 0; ic < 3; ++ic) {
    float win[6][6];
#pragma unroll
    for (int r = 0; r < 6; ++r)
#pragma unroll
      for (int cc = 0; cc < 6; ++cc) win[r][cc] = tile[ic][r0 + r][c0 + cc];
#pragma unroll
    for (int o = 0; o < 16; ++o) {
      const float* __restrict__ wk = cw + ((ocg2 * 16 + o) * 3 + ic) * 25;
#pragma unroll
      for (int kh = 0; kh < 5; ++kh)
#pragma unroll
        for (int kw = 0; kw < 5; ++kw) {
          float wv = wk[kh * 5 + kw];
          acc[o][0] += win[kh][kw] * wv;
          acc[o][1] += win[kh][kw + 1] * wv;
          acc[o][2] += win[kh + 1][kw] * wv;
          acc[o][3] += win[kh + 1][kw + 1] * wv;
        }
    }
  }
#pragma unroll
  for (int o = 0; o < 16; ++o) {
    float m = fmaxf(fmaxf(acc[o][0], acc[o][1]), fmaxf(acc[o][2], acc[o][3]));
    m = fmaxf(m + cb[ocg2 * 16 + o], 0.f);
    pooled[(((size_t)b * 32 + ocg2 * 16 + o) * 128 + ph) * 128 + pw] = m;
  }
}

__device__ __forceinline__ void wc_body(
    const float* __restrict__ w1, const float* __restrict__ w2,
    float* __restrict__ wc, int bx) {
  int i = bx * 256 + threadIdx.x;
  if (i >= 75 * 72) return;
  int r = i / 72, c = i - r * 72;
  float s = 0.f;
  for (int k = 0; k < 288; ++k) s += w1[r * 288 + k] * w2[k * 72 + c];
  wc[i] = s;
}

// ---- K1: conv (4096) + wc (22) ---------------------------------------------
__global__ __launch_bounds__(256) void k1_conv_wc_kernel(
    const float* __restrict__ pic, const float* __restrict__ cw,
    const float* __restrict__ cb, float* __restrict__ pooled,
    const float* __restrict__ gw, const float* __restrict__ gw2,
    float* __restrict__ wcb) {
  __shared__ float tile[3][8][260];
  int bid = blockIdx.x;
  if (bid < 4096) conv_body(pic, cw, cb, pooled, bid, tile);
  else            wc_body(gw, gw2, wcb, bid - 4096);
}

// ------- split-K GEMM body: X[32,K] @ W[K,N] -> partial[split][32][N] ------
// 2 cols/thread (float2 W loads, 8-deep register pipeline). acc = 64 VGPR;
// NO launch_bounds cap (r11 lesson: (256,4) forced 64-VGPR total -> spills).
// chunk % 128 == 0, X rows 16B-aligned.
__device__ __forceinline__ void gemm2c_body(
    const float* __restrict__ X, const float* __restrict__ W,
    float* __restrict__ partial, int K, int N, int chunk,
    int bx, int split, float xs[128][36]) {
  int tid = threadIdx.x;
  int colv = bx * 256 + tid;   // float2 column index
  int col0 = colv * 2;
  bool active = col0 < N;
  int k0 = split * chunk, k1 = min(k0 + chunk, K);
  size_t Nv = (size_t)(N >> 1);
  const float2* Wv = (const float2*)W;
  float2 acc[32];
#pragma unroll
  for (int b = 0; b < 32; ++b) acc[b] = make_float2(0.f, 0.f);

  auto fmablk = [&](int kk, const float2& w2) {
    const float4* xr = (const float4*)xs[kk];
#pragma unroll
    for (int b4 = 0; b4 < 8; ++b4) {
      float4 xv = xr[b4];
      acc[b4 * 4 + 0].x += xv.x * w2.x; acc[b4 * 4 + 0].y += xv.x * w2.y;
      acc[b4 * 4 + 1].x += xv.y * w2.x; acc[b4 * 4 + 1].y += xv.y * w2.y;
      acc[b4 * 4 + 2].x += xv.z * w2.x; acc[b4 * 4 + 2].y += xv.z * w2.y;
      acc[b4 * 4 + 3].x += xv.w * w2.x; acc[b4 * 4 + 3].y += xv.w * w2.y;
    }
  };

  for (int kt = k0; kt < k1; kt += 128) {
    __syncthreads();
#pragma unroll
    for (int j = 0; j < 4; ++j) {
      int idx = tid + j * 256;
      int b = idx >> 5, kk = (idx & 31) * 4;
      float4 x = *(const float4*)&X[(size_t)b * K + kt + kk];
      xs[kk + 0][b] = x.x; xs[kk + 1][b] = x.y;
      xs[kk + 2][b] = x.z; xs[kk + 3][b] = x.w;
    }
    __syncthreads();
    if (active) {
      const float2* wp = Wv + (size_t)kt * Nv + colv;
      float2 cur[8], nxt[8];
#pragma unroll
      for (int j = 0; j < 8; ++j) cur[j] = ntload2(wp + (size_t)j * Nv);
#pragma unroll 1
      for (int g = 0; g < 15; ++g) {
        const float2* wn = wp + 8 * Nv;
#pragma unroll
        for (int j = 0; j < 8; ++j) nxt[j] = ntload2(wn + (size_t)j * Nv);
        int kb = g * 8;
#pragma unroll
        for (int j = 0; j < 8; ++j) fmablk(kb + j, cur[j]);
#pragma unroll
        for (int j = 0; j < 8; ++j) cur[j] = nxt[j];
        wp = wn;
      }
#pragma unroll
      for (int j = 0; j < 8; ++j) fmablk(120 + j, cur[j]);
    }
  }
  if (active) {
    float* p = partial + (size_t)split * 32 * N + col0;
#pragma unroll
    for (int b = 0; b < 32; ++b) *(float2*)(p + (size_t)b * N) = acc[b];
  }
}

// ---- K2: fc1 GEMM (512 blocks) + both mlp GEMMs (1008 blocks) --------------
__global__ __launch_bounds__(256) void gemm_all_kernel(
    const float* __restrict__ pooled, const float* __restrict__ fc1w,
    float* __restrict__ pfc1,
    const float* __restrict__ rna, const float* __restrict__ m1w1, float* __restrict__ pm1,
    const float* __restrict__ cnv, const float* __restrict__ m2w1, float* __restrict__ pm2) {
  __shared__ float xs[128][36];
  int b = blockIdx.x;
  if (b < 512) {
    // fc1: chunk 2048, 256 splits x 2 col-blocks
    gemm2c_body(pooled, fc1w, pfc1, 524288, 1024, 2048, b & 1, b >> 1, xs);
  } else {
    int j = b - 512;          // 0..1007
    int z = j / 504;
    int r = j % 504;
    int bx = r & 7, split = r >> 3;   // split 0..62
    if (z == 0) gemm2c_body(rna, m1w1, pm1, 16000, 4000, 256, bx, split, xs);
    else        gemm2c_body(cnv, m2w1, pm2, 16000, 4000, 256, bx, split, xs);
  }
}

// ---- float4 reduce bodies ---------------------------------------------------
__device__ __forceinline__ void fadd4(float4& a, const float4& v) {
  a.x += v.x; a.y += v.y; a.z += v.z; a.w += v.w;
}

// fc1 stage1: sum 128 splits -> p2[sy][8192 f4]
__device__ __forceinline__ void reduce_s1_body(
    const float* __restrict__ partial, float* __restrict__ p2,
    int bx, int sy) {
  int i = bx * 256 + threadIdx.x;          // f4 index, 8192 per image
  const float4* p = (const float4*)partial + (size_t)(sy * 128) * 8192 + i;
  const size_t st = 8192;
  float4 s0 = make_float4(0, 0, 0, 0), s1 = s0, s2 = s0, s3 = s0;
  for (int sp = 0; sp < 128; sp += 4) {
    fadd4(s0, ntload4(p + (sp + 0) * st));
    fadd4(s1, ntload4(p + (sp + 1) * st));
    fadd4(s2, ntload4(p + (sp + 2) * st));
    fadd4(s3, ntload4(p + (sp + 3) * st));
  }
  float4 r;
  r.x = (s0.x + s1.x) + (s2.x + s3.x);
  r.y = (s0.y + s1.y) + (s2.y + s3.y);
  r.z = (s0.z + s1.z) + (s2.z + s3.z);
  r.w = (s0.w + s1.w) + (s2.w + s3.w);
  ((float4*)p2)[(size_t)sy * 8192 + i] = r;
}

// mlp reduce: nsplit=63, N=4000 (1000 f4/row, 32000 f4 total)
__device__ __forceinline__ void reduce_mlp_body(
    const float* __restrict__ partial, const float* __restrict__ bias,
    float* __restrict__ out, int bx) {
  int i = bx * 256 + threadIdx.x;
  if (i >= 32000) return;
  const float4* p = (const float4*)partial + i;
  const size_t st = 32000;
  float4 s0 = make_float4(0, 0, 0, 0), s1 = s0, s2 = s0, s3 = s0;
  int sp = 0;
  for (; sp + 4 <= 63; sp += 4) {
    fadd4(s0, ntload4(p + (sp + 0) * st));
    fadd4(s1, ntload4(p + (sp + 1) * st));
    fadd4(s2, ntload4(p + (sp + 2) * st));
    fadd4(s3, ntload4(p + (sp + 3) * st));
  }
  for (; sp < 63; ++sp) fadd4(s0, ntload4(p + (size_t)sp * st));
  float4 bi = ((const float4*)bias)[i % 1000];
  float4 r;
  r.x = fmaxf(bi.x + (s0.x + s1.x) + (s2.x + s3.x), 0.f);
  r.y = fmaxf(bi.y + (s0.y + s1.y) + (s2.y + s3.y), 0.f);
  r.z = fmaxf(bi.z + (s0.z + s1.z) + (s2.z + s3.z), 0.f);
  r.w = fmaxf(bi.w + (s0.w + s1.w) + (s2.w + s3.w), 0.f);
  ((float4*)out)[i] = r;
}

// ---- K3: fc1 reduce_s1 (64) + mlp reduces (250) -----------------------------
__global__ __launch_bounds__(256) void k3_reduce_kernel(
    const float* __restrict__ pfc1, float* __restrict__ p2fc1,
    const float* __restrict__ pm1, const float* __restrict__ m1b1, float* __restrict__ h1,
    const float* __restrict__ pm2, const float* __restrict__ m2b1, float* __restrict__ h2) {
  int b = blockIdx.x;
  if (b < 64) {
    reduce_s1_body(pfc1, p2fc1, b & 31, b >> 5);
  } else {
    int idx = b - 64;
    if (idx < 125) reduce_mlp_body(pm1, m1b1, h1, idx);
    else           reduce_mlp_body(pm2, m2b1, h2, idx - 125);
  }
}

// fc1 stage2: bias + 2 sy groups + relu (8192 f4)
__device__ __forceinline__ void reduce_s2_body(
    const float* __restrict__ p2, const float* __restrict__ bias,
    float* __restrict__ out, int bx) {
  int i = bx * 256 + threadIdx.x;
  float4 a = ((const float4*)p2)[i];
  float4 b = ((const float4*)p2)[8192 + i];
  float4 bi = ((const float4*)bias)[i & 255];
  float4 r;
  r.x = fmaxf(bi.x + a.x + b.x, 0.f);
  r.y = fmaxf(bi.y + a.y + b.y, 0.f);
  r.z = fmaxf(bi.z + a.z + b.z, 0.f);
  r.w = fmaxf(bi.w + a.w + b.w, 0.f);
  ((float4*)out)[i] = r;
}

// ------- per-drug GCN body: max(relu(Hn@(Hn@(X@Wc)))), 2x9 blocking --------
__device__ __forceinline__ void gcn_body(
    const float* __restrict__ Xg, const float* __restrict__ Ag,
    const float* __restrict__ Wc, float* __restrict__ drugfea, int d,
    float Hn[64][65], float Xs[64][75], float Wcs[75][72],
    float Ys[64][72], float Ts[64][72]) {
  int tid = threadIdx.x;
  const float* Ad = Ag + (size_t)d * 4096;
  const float* Xd = Xg + (size_t)d * 4800;
  for (int i = tid; i < 4096; i += 256) {
    int r = i & 63, c = i >> 6;
    Hn[r][c] = (r == c) ? 1.f : Ad[c * 64 + r];
  }
  for (int i = tid; i < 4800; i += 256) Xs[i / 75][i % 75] = Xd[i];
  for (int i = tid; i < 5400; i += 256) Wcs[i / 72][i % 72] = Wc[i];
  __syncthreads();
  if (tid < 64) {
    float s = 0.f;
    for (int c = 0; c < 64; ++c) s += Hn[tid][c];
    float inv = (s == 0.f) ? 0.f : 1.f / s;
    for (int c = 0; c < 64; ++c) Hn[tid][c] *= inv;
  }
  __syncthreads();
  int rb = tid >> 3, cb = tid & 7;
  int r0 = rb * 2, c0 = cb * 9;
  {
    float o0[9], o1[9];
#pragma unroll
    for (int j = 0; j < 9; ++j) { o0[j] = 0.f; o1[j] = 0.f; }
    for (int k = 0; k < 75; ++k) {
      float x0 = Xs[r0][k], x1 = Xs[r0 + 1][k];
#pragma unroll
      for (int j = 0; j < 9; ++j) {
        float w = Wcs[k][c0 + j];
        o0[j] += x0 * w; o1[j] += x1 * w;
      }
    }
#pragma unroll
    for (int j = 0; j < 9; ++j) { Ys[r0][c0 + j] = o0[j]; Ys[r0 + 1][c0 + j] = o1[j]; }
  }
  __syncthreads();
  {
    float o0[9], o1[9];
#pragma unroll
    for (int j = 0; j < 9; ++j) { o0[j] = 0.f; o1[j] = 0.f; }
    for (int k = 0; k < 64; ++k) {
      float x0 = Hn[r0][k], x1 = Hn[r0 + 1][k];
#pragma unroll
      for (int j = 0; j < 9; ++j) {
        float w = Ys[k][c0 + j];
        o0[j] += x0 * w; o1[j] += x1 * w;
      }
    }
#pragma unroll
    for (int j = 0; j < 9; ++j) { Ts[r0][c0 + j] = o0[j]; Ts[r0 + 1][c0 + j] = o1[j]; }
  }
  __syncthreads();
  {
    float o0[9], o1[9];
#pragma unroll
    for (int j = 0; j < 9; ++j) { o0[j] = 0.f; o1[j] = 0.f; }
    for (int k = 0; k < 64; ++k) {
      float x0 = Hn[r0][k], x1 = Hn[r0 + 1][k];
#pragma unroll
      for (int j = 0; j < 9; ++j) {
        float w = Ts[k][c0 + j];
        o0[j] += x0 * w; o1[j] += x1 * w;
      }
    }
#pragma unroll
    for (int j = 0; j < 9; ++j) {
      Ys[r0][c0 + j] = fmaxf(o0[j], 0.f);
      Ys[r0 + 1][c0 + j] = fmaxf(o1[j], 0.f);
    }
  }
  __syncthreads();
  if (tid < 72) {
    float m = Ys[0][tid];
    for (int i = 1; i < 64; ++i) m = fmaxf(m, Ys[i][tid]);
    drugfea[d * 72 + tid] = m;
  }
}

// ---- K4: fc1 reduce_s2 (32) + gcn (128) -------------------------------------
__global__ __launch_bounds__(256) void k4_s2_gcn_kernel(
    const float* __restrict__ p2fc1, const float* __restrict__ fc1_b,
    float* __restrict__ fcact,
    const float* __restrict__ Xg, const float* __restrict__ Ag,
    const float* __restrict__ wcb, float* __restrict__ drugfea) {
  __shared__ float Hn[64][65];
  __shared__ float Xs[64][75];
  __shared__ float Wcs[75][72];
  __shared__ float Ys[64][72];
  __shared__ float Ts[64][72];
  int b = blockIdx.x;
  if (b < 32) reduce_s2_body(p2fc1, fc1_b, fcact, b);
  else        gcn_body(Xg, Ag, wcb, drugfea, b - 32, Hn, Xs, Wcs, Ys, Ts);
}

// ------- x[32,K] @ W[K,36] + b, 3 branches fused, float4 W loads -----------
__global__ __launch_bounds__(256) void lin36_all_kernel(
    const float* __restrict__ X0, const float* __restrict__ W0,
    const float* __restrict__ bi0, float* __restrict__ out0,
    const float* __restrict__ X1, const float* __restrict__ W1,
    const float* __restrict__ bi1, float* __restrict__ out1,
    const float* __restrict__ X2, const float* __restrict__ W2,
    const float* __restrict__ bi2, float* __restrict__ out2) {
  const float* X; const float* W; const float* bias; float* out; int K; bool do_sm;
  if (blockIdx.y == 0)      { X = X0; W = W0; bias = bi0; out = out0; K = 4000; do_sm = true; }
  else if (blockIdx.y == 1) { X = X1; W = W1; bias = bi1; out = out1; K = 4000; do_sm = true; }
  else                      { X = X2; W = W2; bias = bi2; out = out2; K = 1024; do_sm = false; }
  __shared__ float xs[4000];
  __shared__ float red[28][36];
  __shared__ float vals[36];
  __shared__ float mxv, smv;
  int b = blockIdx.x, tid = threadIdx.x;
  for (int i = tid; i < K; i += 256) xs[i] = X[(size_t)b * K + i];
  __syncthreads();
  if (tid < 252) {
    int c4 = tid % 9, g = tid / 9;
    const float4* W4 = (const float4*)W;
    float4 s = make_float4(0.f, 0.f, 0.f, 0.f);
    for (int k = g; k < K; k += 28) fma4(s, xs[k], W4[k * 9 + c4]);
    red[g][c4 * 4 + 0] = s.x; red[g][c4 * 4 + 1] = s.y;
    red[g][c4 * 4 + 2] = s.z; red[g][c4 * 4 + 3] = s.w;
  }
  __syncthreads();
  if (tid < 36) {
    float s = bias[tid];
    for (int g = 0; g < 28; ++g) s += red[g][tid];
    vals[tid] = s;
  }
  __syncthreads();
  if (do_sm) {
    if (tid == 0) {
      float m = -1e30f;
      for (int j = 0; j < 36; ++j) m = fmaxf(m, vals[j]);
      float e = 0.f;
      for (int j = 0; j < 36; ++j) e += expf(vals[j] - m);
      mxv = m; smv = e;
    }
    __syncthreads();
    if (tid < 36) out[b * 36 + tid] = expf(vals[tid] - mxv) / smv;
  } else {
    if (tid < 36) out[b * 36 + tid] = vals[tid];
  }
}

// ---------------- attention + CLIP loss + cell_cat (single block) ----------
__global__ __launch_bounds__(256) void head_kernel(
    const float* __restrict__ rna1, const float* __restrict__ cnv1,
    const float* __restrict__ pic1r, const float* __restrict__ aw1,
    const float* __restrict__ ab1, const float* __restrict__ aw2,
    const float* __restrict__ scale_p, float* __restrict__ cell_cat,
    float* __restrict__ dout) {
  __shared__ float z[2][32][36];
  __shared__ float pic1n[32][36];
  __shared__ float celln[32][36];
  __shared__ float fea[32][32];
  __shared__ float wvp[64];
  __shared__ float beta0, beta1;
  __shared__ float rowl[32], coll[32];
  int tid = threadIdx.x;
  for (int i = tid; i < 1152; i += 256) {
    int b = i / 36, k = i - (i / 36) * 36;
    z[0][b][k] = rna1[i];
    z[1][b][k] = cnv1[i];
    pic1n[b][k] = pic1r[i];
  }
  __syncthreads();
  {
    int p = tid >> 2, sub = tid & 3;
    int b = p >> 1, v = p & 1;
    float s = 0.f;
    for (int h = sub; h < 128; h += 4) {
      float a = ab1[h];
      for (int k = 0; k < 36; ++k) a += z[v][b][k] * aw1[k * 128 + h];
      s += tanhf(a) * aw2[h];
    }
    s += __shfl_down(s, 1, 64);
    s += __shfl_down(s, 2, 64);
    if (sub == 0) wvp[p] = s;
  }
  __syncthreads();
  if (tid == 0) {
    float w0 = 0.f, w1 = 0.f;
    for (int b = 0; b < 32; ++b) { w0 += wvp[b * 2]; w1 += wvp[b * 2 + 1]; }
    w0 /= 32.f; w1 /= 32.f;
    float m = fmaxf(w0, w1);
    float e0 = expf(w0 - m), e1 = expf(w1 - m);
    beta0 = e0 / (e0 + e1); beta1 = e1 / (e0 + e1);
  }
  __syncthreads();
  for (int i = tid; i < 1152; i += 256) {
    int b = i / 36, k = i - (i / 36) * 36;
    celln[b][k] = beta0 * z[0][b][k] + beta1 * z[1][b][k];
  }
  __syncthreads();
  if (tid < 32) {
    float s = 0.f;
    for (int k = 0; k < 36; ++k) { float x = pic1n[tid][k]; s += x * x; }
    float inv = 1.f / sqrtf(s);
    for (int k = 0; k < 36; ++k) pic1n[tid][k] *= inv;
  } else if (tid < 64) {
    int b = tid - 32;
    float s = 0.f;
    for (int k = 0; k < 36; ++k) { float x = celln[b][k]; s += x * x; }
    float inv = 1.f / sqrtf(s);
    for (int k = 0; k < 36; ++k) celln[b][k] *= inv;
  }
  __syncthreads();
  for (int i = tid; i < 1152; i += 256) {
    int b = i / 36, k = i - (i / 36) * 36;
    cell_cat[b * 72 + k] = celln[b][k];
    cell_cat[b * 72 + 36 + k] = pic1n[b][k];
  }
  float sc = *scale_p;
  for (int t = tid; t < 1024; t += 256) {
    int i = t >> 5, j = t & 31;
    float s = 0.f;
    for (int k = 0; k < 36; ++k) s += pic1n[i][k] * celln[j][k];
    fea[i][j] = sc * s;
  }
  __syncthreads();
  if (tid < 32) {
    float m = -1e30f;
    for (int j = 0; j < 32; ++j) m = fmaxf(m, fea[tid][j]);
    float e = 0.f;
    for (int j = 0; j < 32; ++j) e += expf(fea[tid][j] - m);
    rowl[tid] = (logf(e) + m) - fea[tid][tid];
  } else if (tid < 64) {
    int j = tid - 32;
    float m = -1e30f;
    for (int i = 0; i < 32; ++i) m = fmaxf(m, fea[i][j]);
    float e = 0.f;
    for (int i = 0; i < 32; ++i) e += expf(fea[i][j] - m);
    coll[j] = (logf(e) + m) - fea[j][j];
  }
  __syncthreads();
  if (tid == 0) {
    float s1 = 0.f, s2 = 0.f;
    for (int i = 0; i < 32; ++i) { s1 += rowl[i]; s2 += coll[i]; }
    dout[1] = 0.5f * (s1 / 32.f + s2 / 32.f);
  }
}

// ---------------- pair head + per-block CE partial sums --------------------
__global__ __launch_bounds__(256) void pair_kernel(
    const float* __restrict__ cell_cat, const float* __restrict__ drugfea,
    const int* __restrict__ idx, const int* __restrict__ target,
    const float* __restrict__ w1, const float* __restrict__ b1,
    const float* __restrict__ w2, const float* __restrict__ b2,
    float* __restrict__ bp_out, float* __restrict__ tgt_out,
    float* __restrict__ blocksums) {
  __shared__ float w1s[144][36];
  __shared__ float ccs[32][73];
  __shared__ float dfs[128][73];
  __shared__ float w2s[72], b2s[2];
  __shared__ float lsum[256];
  int tid = threadIdx.x;
  {
    float4* dst = (float4*)&w1s[0][0];
    const float4* src = (const float4*)w1;
    for (int i = tid; i < 1296; i += 256) dst[i] = src[i];
  }
  for (int i = tid; i < 2304; i += 256) ccs[i / 72][i % 72] = cell_cat[i];
  for (int i = tid; i < 9216; i += 256) dfs[i / 72][i % 72] = drugfea[i];
  if (tid < 72) w2s[tid] = w2[tid];
  if (tid < 2) b2s[tid] = b2[tid];
  __syncthreads();
  int p = blockIdx.x * 256 + tid;
  int ci = idx[p * 2], dj = idx[p * 2 + 1];
  float4 h4[9];
  {
    const float4* bb = (const float4*)b1;
#pragma unroll
    for (int q = 0; q < 9; ++q) h4[q] = bb[q];
  }
  for (int k = 0; k < 72; ++k) {
    float x = ccs[ci][k];
    const float4* wr = (const float4*)&w1s[k][0];
#pragma unroll
    for (int q = 0; q < 9; ++q) fma4(h4[q], x, wr[q]);
  }
  for (int k = 0; k < 72; ++k) {
    float x = dfs[dj][k];
    const float4* wr = (const float4*)&w1s[72 + k][0];
#pragma unroll
    for (int q = 0; q < 9; ++q) fma4(h4[q], x, wr[q]);
  }
  float l0 = b2s[0], l1 = b2s[1];
#pragma unroll
  for (int q = 0; q < 9; ++q) {
    float hv;
    hv = fmaxf(h4[q].x, 0.f); l0 += hv * w2s[(q * 4 + 0) * 2]; l1 += hv * w2s[(q * 4 + 0) * 2 + 1];
    hv = fmaxf(h4[q].y, 0.f); l0 += hv * w2s[(q * 4 + 1) * 2]; l1 += hv * w2s[(q * 4 + 1) * 2 + 1];
    hv = fmaxf(h4[q].z, 0.f); l0 += hv * w2s[(q * 4 + 2) * 2]; l1 += hv * w2s[(q * 4 + 2) * 2 + 1];
    hv = fmaxf(h4[q].w, 0.f); l0 += hv * w2s[(q * 4 + 3) * 2]; l1 += hv * w2s[(q * 4 + 3) * 2 + 1];
  }
  float m = fmaxf(l0, l1);
  float e0 = expf(l0 - m), e1 = expf(l1 - m);
  float inv = 1.f / (e0 + e1);
  float p0 = e0 * inv, p1 = e1 * inv;
  bp_out[p * 2] = p0;
  bp_out[p * 2 + 1] = p1;
  int t = target[p];
  float mm = fmaxf(p0, p1);
  float lse = logf(expf(p0 - mm) + expf(p1 - mm)) + mm;
  float chosen = t ? p1 : p0;
  lsum[tid] = lse - chosen;
  tgt_out[p] = (float)t;
  __syncthreads();
  for (int s = 128; s > 0; s >>= 1) {
    if (tid < s) lsum[tid] += lsum[tid + s];
    __syncthreads();
  }
  if (tid == 0) blocksums[blockIdx.x] = lsum[0];
}

__global__ void final_kernel(const float* __restrict__ blocksums, float* __restrict__ dout) {
  if (threadIdx.x == 0 && blockIdx.x == 0) {
    float s = 0.f;
    for (int i = 0; i < 16; ++i) s += blocksums[i];
    dout[0] = s / 4096.f;
  }
}

extern "C" void kernel_launch(void* const* d_in, const int* in_sizes, int n_in,
                              void* d_out, int out_size, void* d_ws, size_t ws_size,
                              hipStream_t stream) {
  (void)in_sizes; (void)n_in; (void)out_size; (void)ws_size;
  const float* pic        = (const float*)d_in[0];
  const float* rna        = (const float*)d_in[1];
  const float* cnv        = (const float*)d_in[2];
  const float* drug_fea   = (const float*)d_in[3];
  const float* drug_adj   = (const float*)d_in[4];
  const int*   index_list = (const int*)d_in[5];
  const int*   target     = (const int*)d_in[6];
  const float* logit_scale= (const float*)d_in[7];
  const float* conv_w     = (const float*)d_in[8];
  const float* conv_b     = (const float*)d_in[9];
  const float* fc1_w      = (const float*)d_in[10];
  const float* fc1_b      = (const float*)d_in[11];
  const float* fc2_w      = (const float*)d_in[12];
  const float* fc2_b      = (const float*)d_in[13];
  const float* m1w1       = (const float*)d_in[14];
  const float* m1b1       = (const float*)d_in[15];
  const float* m1w2       = (const float*)d_in[16];
  const float* m1b2       = (const float*)d_in[17];
  const float* m2w1       = (const float*)d_in[18];
  const float* m2b1       = (const float*)d_in[19];
  const float* m2w2       = (const float*)d_in[20];
  const float* m2b2       = (const float*)d_in[21];
  const float* aw1        = (const float*)d_in[22];
  const float* ab1        = (const float*)d_in[23];
  const float* aw2        = (const float*)d_in[24];
  const float* ew1        = (const float*)d_in[25];
  const float* eb1        = (const float*)d_in[26];
  const float* ew2        = (const float*)d_in[27];
  const float* eb2        = (const float*)d_in[28];
  const float* gw         = (const float*)d_in[29];
  const float* gw2        = (const float*)d_in[30];

  float* ws = (float*)d_ws;
  float* pooled  = ws;                   // 16,777,216 f
  float* pfc1    = ws + 16777216;        //  8,388,608 f (256*32*1024)
  float* p2fc1   = ws + 33554432;        //     65,536 f (2*32*1024)
  float* pm1     = ws + 33685504;        //  8,064,000 f (63*32*4000)
  float* pm2     = ws + 41749504;        //  8,064,000 f
  float* fcact   = ws + 49813504;        //     32,768 f
  float* h1      = ws + 49846272;        //    128,000 f
  float* h2      = ws + 49974272;        //    128,000 f
  float* rna1    = ws + 50102272;        //      1,152 f
  float* cnv1    = ws + 50103424;
  float* pic1r   = ws + 50104576;
  float* wcb     = ws + 50105728;        //      5,400 f
  float* drugf   = ws + 50111128;        //      9,216 f
  float* cellcat = ws + 50120344;        //      2,304 f
  float* bsums   = ws + 50122648;        //         16 f

  float* out = (float*)d_out;

  // K1: conv (4096) + wc (22)
  k1_conv_wc_kernel<<<4118, 256, 0, stream>>>(pic, conv_w, conv_b, pooled,
                                              gw, gw2, wcb);
  // K2: fc1 GEMM (512) + mlp GEMMs (1008); 2 cols/thread, natural VGPR
  gemm_all_kernel<<<1520, 256, 0, stream>>>(pooled, fc1_w, pfc1,
                                            rna, m1w1, pm1, cnv, m2w1, pm2);
  // K3: fc1 reduce stage1 (64) || mlp reduces (250), float4
  k3_reduce_kernel<<<314, 256, 0, stream>>>(pfc1, p2fc1,
                                            pm1, m1b1, h1, pm2, m2b1, h2);
  // K4: fc1 reduce stage2 (32) || drug GCN (128)
  k4_s2_gcn_kernel<<<160, 256, 0, stream>>>(p2fc1, fc1_b, fcact,
                                            drug_fea, drug_adj, wcb, drugf);
  // K5: the three 36-col linears (+softmax)
  {
    dim3 g(32, 3);
    lin36_all_kernel<<<g, 256, 0, stream>>>(h1, m1w2, m1b2, rna1,
                                            h2, m2w2, m2b2, cnv1,
                                            fcact, fc2_w, fc2_b, pic1r);
  }
  // K6: attention + CLIP loss
  head_kernel<<<1, 256, 0, stream>>>(rna1, cnv1, pic1r, aw1, ab1, aw2,
                                     logit_scale, cellcat, out);
  // K7: pair prediction head
  pair_kernel<<<16, 256, 0, stream>>>(cellcat, drugf, index_list, target,
                                      ew1, eb1, ew2, eb2,
                                      out + 2, out + 2 + 8192, bsums);
  // K8: final CE mean
  final_kernel<<<1, 64, 0, stream>>>(bsums, out);
}

// Round 13
// 1002.761 us; speedup vs baseline: 1.9875x; 1.1191x over previous
//
#include <hip/hip_runtime.h>
#include <hip/hip_bf16.h>
#include <math.h>

typedef float evf4 __attribute__((ext_vector_type(4)));

__device__ __forceinline__ void fma4(float4& a, float s, const float4& v) {
  a.x += s * v.x; a.y += s * v.y; a.z += s * v.z; a.w += s * v.w;
}
__device__ __forceinline__ void fadd4(float4& a, const float4& v) {
  a.x += v.x; a.y += v.y; a.z += v.z; a.w += v.w;
}
__device__ __forceinline__ float4 ntload4(const float4* p) {
  evf4 v = __builtin_nontemporal_load((const evf4*)p);
  return make_float4(v.x, v.y, v.z, v.w);
}

// ---------------- conv body: conv(3->32,k5,p2) + relu + maxpool2 -----------
__device__ __forceinline__ void conv_body(
    const float* __restrict__ pic, const float* __restrict__ cw,
    const float* __restrict__ cb, float* __restrict__ pooled,
    int bid, float tile[3][8][260]) {
  int php = bid & 63, ocg2 = (bid >> 6) & 1, b = bid >> 7;
  int tid = threadIdx.x;
  int pw = tid & 127, phl = tid >> 7;
  int ph = php * 2 + phl;
  int h_base = php * 4 - 2;
  for (int i = tid; i < 3 * 8 * 260; i += 256) {
    int c = i % 260; int rr = (i / 260) & 7; int ic = i / (260 * 8);
    int h = h_base + rr, w = c - 2;
    float v = 0.f;
    if (h >= 0 && h < 256 && w >= 0 && w < 256)
      v = pic[((size_t)b * 3 + ic) * 65536 + h * 256 + w];
    tile[ic][rr][c] = v;
  }
  __syncthreads();
  float acc[16][4];
#pragma unroll
  for (int o = 0; o < 16; ++o)
#pragma unroll
    for (int q = 0; q < 4; ++q) acc[o][q] = 0.f;
  int r0 = phl * 2;
  int c0 = pw * 2;
#pragma unroll
  for (int ic = 0; ic < 3; ++ic) {
    float win[6][6];
#pragma unroll
    for (int r = 0; r < 6; ++r)
#pragma unroll
      for (int cc = 0; cc < 6; ++cc) win[r][cc] = tile[ic][r0 + r][c0 + cc];
#pragma unroll
    for (int o = 0; o < 16; ++o) {
      const float* __restrict__ wk = cw + ((ocg2 * 16 + o) * 3 + ic) * 25;
#pragma unroll
      for (int kh = 0; kh < 5; ++kh)
#pragma unroll
        for (int kw = 0; kw < 5; ++kw) {
          float wv = wk[kh * 5 + kw];
          acc[o][0] += win[kh][kw] * wv;
          acc[o][1] += win[kh][kw + 1] * wv;
          acc[o][2] += win[kh + 1][kw] * wv;
          acc[o][3] += win[kh + 1][kw + 1] * wv;
        }
    }
  }
#pragma unroll
  for (int o = 0; o < 16; ++o) {
    float m = fmaxf(fmaxf(acc[o][0], acc[o][1]), fmaxf(acc[o][2], acc[o][3]));
    m = fmaxf(m + cb[ocg2 * 16 + o], 0.f);
    pooled[(((size_t)b * 32 + ocg2 * 16 + o) * 128 + ph) * 128 + pw] = m;
  }
}

__device__ __forceinline__ void wc_body(
    const float* __restrict__ w1, const float* __restrict__ w2,
    float* __restrict__ wc, int bx) {
  int i = bx * 256 + threadIdx.x;
  if (i >= 75 * 72) return;
  int r = i / 72, c = i - r * 72;
  float s = 0.f;
  for (int k = 0; k < 288; ++k) s += w1[r * 288 + k] * w2[k * 72 + c];
  wc[i] = s;
}

// ---- K1: conv (4096) + wc (22) ---------------------------------------------
__global__ __launch_bounds__(256) void k1_conv_wc_kernel(
    const float* __restrict__ pic, const float* __restrict__ cw,
    const float* __restrict__ cb, float* __restrict__ pooled,
    const float* __restrict__ gw, const float* __restrict__ gw2,
    float* __restrict__ wcb) {
  __shared__ float tile[3][8][260];
  int bid = blockIdx.x;
  if (bid < 4096) conv_body(pic, cw, cb, pooled, bid, tile);
  else            wc_body(gw, gw2, wcb, bid - 4096);
}

// ------- split-K GEMM body: X[32,K] @ W[K,N] -> partial[split][32][N] ------
// 4 cols/thread, 8-deep W register pipeline (nontemporal), async X-tile
// register prefetch. chunk % 128 == 0, X rows 16B-aligned. (r10-proven.)
__device__ __forceinline__ void gemm32p_body(
    const float* __restrict__ X, const float* __restrict__ W,
    float* __restrict__ partial, int K, int N, int chunk,
    int bx, int split, float xs[128][36]) {
  int tid = threadIdx.x;
  int colv = bx * 256 + tid;
  int col0 = colv * 4;
  bool active = col0 < N;
  int k0 = split * chunk, k1 = min(k0 + chunk, K);
  size_t Nv = (size_t)(N >> 2);
  const float4* Wv = (const float4*)W;
  float4 acc[32];
#pragma unroll
  for (int b = 0; b < 32; ++b) acc[b] = make_float4(0.f, 0.f, 0.f, 0.f);

  float4 xpre[4];
#pragma unroll
  for (int j = 0; j < 4; ++j) {
    int idx = tid + j * 256;
    int b = idx >> 5, kk = (idx & 31) * 4;
    xpre[j] = *(const float4*)&X[(size_t)b * K + k0 + kk];
  }

  auto fmablk = [&](int kk, const float4& w4) {
    const float4* xr = (const float4*)xs[kk];
#pragma unroll
    for (int b4 = 0; b4 < 8; ++b4) {
      float4 xv = xr[b4];
      fma4(acc[b4 * 4 + 0], xv.x, w4);
      fma4(acc[b4 * 4 + 1], xv.y, w4);
      fma4(acc[b4 * 4 + 2], xv.z, w4);
      fma4(acc[b4 * 4 + 3], xv.w, w4);
    }
  };

  for (int kt = k0; kt < k1; kt += 128) {
    __syncthreads();
#pragma unroll
    for (int j = 0; j < 4; ++j) {
      int idx = tid + j * 256;
      int b = idx >> 5, kk = (idx & 31) * 4;
      xs[kk + 0][b] = xpre[j].x;
      xs[kk + 1][b] = xpre[j].y;
      xs[kk + 2][b] = xpre[j].z;
      xs[kk + 3][b] = xpre[j].w;
    }
    __syncthreads();
    if (kt + 128 < k1) {
#pragma unroll
      for (int j = 0; j < 4; ++j) {
        int idx = tid + j * 256;
        int b = idx >> 5, kk = (idx & 31) * 4;
        xpre[j] = *(const float4*)&X[(size_t)b * K + kt + 128 + kk];
      }
    }
    if (active) {
      const float4* wp = Wv + (size_t)kt * Nv + colv;
      float4 cur[8], nxt[8];
#pragma unroll
      for (int j = 0; j < 8; ++j) cur[j] = ntload4(wp + (size_t)j * Nv);
#pragma unroll 1
      for (int g = 0; g < 15; ++g) {
        const float4* wn = wp + 8 * Nv;
#pragma unroll
        for (int j = 0; j < 8; ++j) nxt[j] = ntload4(wn + (size_t)j * Nv);
        int kb = g * 8;
#pragma unroll
        for (int j = 0; j < 8; ++j) fmablk(kb + j, cur[j]);
#pragma unroll
        for (int j = 0; j < 8; ++j) cur[j] = nxt[j];
        wp = wn;
      }
#pragma unroll
      for (int j = 0; j < 8; ++j) fmablk(120 + j, cur[j]);
    }
  }
  if (active) {
    float* p = partial + (size_t)split * 32 * N + col0;
#pragma unroll
    for (int b = 0; b < 32; ++b) *(float4*)(p + (size_t)b * N) = acc[b];
  }
}

// ---- K2: fc1 GEMM (512 blocks) + both mlp GEMMs (504 blocks) ---------------
__global__ __launch_bounds__(256) void gemm_all_kernel(
    const float* __restrict__ pooled, const float* __restrict__ fc1w,
    float* __restrict__ pfc1,
    const float* __restrict__ rna, const float* __restrict__ m1w1, float* __restrict__ pm1,
    const float* __restrict__ cnv, const float* __restrict__ m2w1, float* __restrict__ pm2) {
  __shared__ float xs[128][36];
  int b = blockIdx.x;
  if (b < 512) {
    gemm32p_body(pooled, fc1w, pfc1, 524288, 1024, 1024, 0, b, xs);
  } else {
    int j = b - 512;          // 0..503
    int z = j / 252;
    int r = j % 252;
    int bx = r & 3, split = r >> 2;   // split 0..62
    if (z == 0) gemm32p_body(rna, m1w1, pm1, 16000, 4000, 256, bx, split, xs);
    else        gemm32p_body(cnv, m2w1, pm2, 16000, 4000, 256, bx, split, xs);
  }
}

// ---- float4 reduce bodies ---------------------------------------------------
// fc1 stage1: 512 splits -> 4 sy-groups of 128; p2[sy][8192 f4]
__device__ __forceinline__ void reduce_s1_body(
    const float* __restrict__ partial, float* __restrict__ p2,
    int bx, int sy) {
  int i = bx * 256 + threadIdx.x;          // f4 index, 8192 per group
  const float4* p = (const float4*)partial + (size_t)(sy * 128) * 8192 + i;
  const size_t st = 8192;
  float4 s0 = make_float4(0, 0, 0, 0), s1 = s0, s2 = s0, s3 = s0;
  for (int sp = 0; sp < 128; sp += 4) {
    fadd4(s0, ntload4(p + (sp + 0) * st));
    fadd4(s1, ntload4(p + (sp + 1) * st));
    fadd4(s2, ntload4(p + (sp + 2) * st));
    fadd4(s3, ntload4(p + (sp + 3) * st));
  }
  float4 r;
  r.x = (s0.x + s1.x) + (s2.x + s3.x);
  r.y = (s0.y + s1.y) + (s2.y + s3.y);
  r.z = (s0.z + s1.z) + (s2.z + s3.z);
  r.w = (s0.w + s1.w) + (s2.w + s3.w);
  ((float4*)p2)[(size_t)sy * 8192 + i] = r;
}

// mlp reduce: nsplit=63, N=4000 (1000 f4/row, 32000 f4 total)
__device__ __forceinline__ void reduce_mlp_body(
    const float* __restrict__ partial, const float* __restrict__ bias,
    float* __restrict__ out, int bx) {
  int i = bx * 256 + threadIdx.x;
  if (i >= 32000) return;
  const float4* p = (const float4*)partial + i;
  const size_t st = 32000;
  float4 s0 = make_float4(0, 0, 0, 0), s1 = s0, s2 = s0, s3 = s0;
  int sp = 0;
  for (; sp + 4 <= 63; sp += 4) {
    fadd4(s0, ntload4(p + (sp + 0) * st));
    fadd4(s1, ntload4(p + (sp + 1) * st));
    fadd4(s2, ntload4(p + (sp + 2) * st));
    fadd4(s3, ntload4(p + (sp + 3) * st));
  }
  for (; sp < 63; ++sp) fadd4(s0, ntload4(p + (size_t)sp * st));
  float4 bi = ((const float4*)bias)[i % 1000];
  float4 r;
  r.x = fmaxf(bi.x + (s0.x + s1.x) + (s2.x + s3.x), 0.f);
  r.y = fmaxf(bi.y + (s0.y + s1.y) + (s2.y + s3.y), 0.f);
  r.z = fmaxf(bi.z + (s0.z + s1.z) + (s2.z + s3.z), 0.f);
  r.w = fmaxf(bi.w + (s0.w + s1.w) + (s2.w + s3.w), 0.f);
  ((float4*)out)[i] = r;
}

// ---- K3: fc1 reduce_s1 (128) + mlp reduces (250) ----------------------------
__global__ __launch_bounds__(256) void k3_reduce_kernel(
    const float* __restrict__ pfc1, float* __restrict__ p2fc1,
    const float* __restrict__ pm1, const float* __restrict__ m1b1, float* __restrict__ h1,
    const float* __restrict__ pm2, const float* __restrict__ m2b1, float* __restrict__ h2) {
  int b = blockIdx.x;
  if (b < 128) {
    reduce_s1_body(pfc1, p2fc1, b & 31, b >> 5);
  } else {
    int idx = b - 128;
    if (idx < 125) reduce_mlp_body(pm1, m1b1, h1, idx);
    else           reduce_mlp_body(pm2, m2b1, h2, idx - 125);
  }
}

// fc1 stage2: bias + 4 sy groups + relu (8192 f4, 32 blocks)
__device__ __forceinline__ void reduce_s2_body(
    const float* __restrict__ p2, const float* __restrict__ bias,
    float* __restrict__ out, int bx) {
  int i = bx * 256 + threadIdx.x;
  float4 a = ((const float4*)p2)[i];
  float4 b = ((const float4*)p2)[8192 + i];
  float4 c = ((const float4*)p2)[16384 + i];
  float4 d = ((const float4*)p2)[24576 + i];
  float4 bi = ((const float4*)bias)[i & 255];
  float4 r;
  r.x = fmaxf(bi.x + (a.x + b.x) + (c.x + d.x), 0.f);
  r.y = fmaxf(bi.y + (a.y + b.y) + (c.y + d.y), 0.f);
  r.z = fmaxf(bi.z + (a.z + b.z) + (c.z + d.z), 0.f);
  r.w = fmaxf(bi.w + (a.w + b.w) + (c.w + d.w), 0.f);
  ((float4*)out)[i] = r;
}

// ------- per-drug GCN body: max(relu(Hn@(Hn@(X@Wc)))), 2x9 blocking --------
__device__ __forceinline__ void gcn_body(
    const float* __restrict__ Xg, const float* __restrict__ Ag,
    const float* __restrict__ Wc, float* __restrict__ drugfea, int d,
    float Hn[64][65], float Xs[64][75], float Wcs[75][72],
    float Ys[64][72], float Ts[64][72]) {
  int tid = threadIdx.x;
  const float* Ad = Ag + (size_t)d * 4096;
  const float* Xd = Xg + (size_t)d * 4800;
  for (int i = tid; i < 4096; i += 256) {
    int r = i & 63, c = i >> 6;
    Hn[r][c] = (r == c) ? 1.f : Ad[c * 64 + r];
  }
  for (int i = tid; i < 4800; i += 256) Xs[i / 75][i % 75] = Xd[i];
  for (int i = tid; i < 5400; i += 256) Wcs[i / 72][i % 72] = Wc[i];
  __syncthreads();
  if (tid < 64) {
    float s = 0.f;
    for (int c = 0; c < 64; ++c) s += Hn[tid][c];
    float inv = (s == 0.f) ? 0.f : 1.f / s;
    for (int c = 0; c < 64; ++c) Hn[tid][c] *= inv;
  }
  __syncthreads();
  int rb = tid >> 3, cb = tid & 7;
  int r0 = rb * 2, c0 = cb * 9;
  {
    float o0[9], o1[9];
#pragma unroll
    for (int j = 0; j < 9; ++j) { o0[j] = 0.f; o1[j] = 0.f; }
    for (int k = 0; k < 75; ++k) {
      float x0 = Xs[r0][k], x1 = Xs[r0 + 1][k];
#pragma unroll
      for (int j = 0; j < 9; ++j) {
        float w = Wcs[k][c0 + j];
        o0[j] += x0 * w; o1[j] += x1 * w;
      }
    }
#pragma unroll
    for (int j = 0; j < 9; ++j) { Ys[r0][c0 + j] = o0[j]; Ys[r0 + 1][c0 + j] = o1[j]; }
  }
  __syncthreads();
  {
    float o0[9], o1[9];
#pragma unroll
    for (int j = 0; j < 9; ++j) { o0[j] = 0.f; o1[j] = 0.f; }
    for (int k = 0; k < 64; ++k) {
      float x0 = Hn[r0][k], x1 = Hn[r0 + 1][k];
#pragma unroll
      for (int j = 0; j < 9; ++j) {
        float w = Ys[k][c0 + j];
        o0[j] += x0 * w; o1[j] += x1 * w;
      }
    }
#pragma unroll
    for (int j = 0; j < 9; ++j) { Ts[r0][c0 + j] = o0[j]; Ts[r0 + 1][c0 + j] = o1[j]; }
  }
  __syncthreads();
  {
    float o0[9], o1[9];
#pragma unroll
    for (int j = 0; j < 9; ++j) { o0[j] = 0.f; o1[j] = 0.f; }
    for (int k = 0; k < 64; ++k) {
      float x0 = Hn[r0][k], x1 = Hn[r0 + 1][k];
#pragma unroll
      for (int j = 0; j < 9; ++j) {
        float w = Ts[k][c0 + j];
        o0[j] += x0 * w; o1[j] += x1 * w;
      }
    }
#pragma unroll
    for (int j = 0; j < 9; ++j) {
      Ys[r0][c0 + j] = fmaxf(o0[j], 0.f);
      Ys[r0 + 1][c0 + j] = fmaxf(o1[j], 0.f);
    }
  }
  __syncthreads();
  if (tid < 72) {
    float m = Ys[0][tid];
    for (int i = 1; i < 64; ++i) m = fmaxf(m, Ys[i][tid]);
    drugfea[d * 72 + tid] = m;
  }
}

// ---- K4: fc1 reduce_s2 (32) + gcn (128) -------------------------------------
__global__ __launch_bounds__(256) void k4_s2_gcn_kernel(
    const float* __restrict__ p2fc1, const float* __restrict__ fc1_b,
    float* __restrict__ fcact,
    const float* __restrict__ Xg, const float* __restrict__ Ag,
    const float* __restrict__ wcb, float* __restrict__ drugfea) {
  __shared__ float Hn[64][65];
  __shared__ float Xs[64][75];
  __shared__ float Wcs[75][72];
  __shared__ float Ys[64][72];
  __shared__ float Ts[64][72];
  int b = blockIdx.x;
  if (b < 32) reduce_s2_body(p2fc1, fc1_b, fcact, b);
  else        gcn_body(Xg, Ag, wcb, drugfea, b - 32, Hn, Xs, Wcs, Ys, Ts);
}

// ------- x[32,K] @ W[K,36] + b, 3 branches fused, float4 W loads -----------
__global__ __launch_bounds__(256) void lin36_all_kernel(
    const float* __restrict__ X0, const float* __restrict__ W0,
    const float* __restrict__ bi0, float* __restrict__ out0,
    const float* __restrict__ X1, const float* __restrict__ W1,
    const float* __restrict__ bi1, float* __restrict__ out1,
    const float* __restrict__ X2, const float* __restrict__ W2,
    const float* __restrict__ bi2, float* __restrict__ out2) {
  const float* X; const float* W; const float* bias; float* out; int K; bool do_sm;
  if (blockIdx.y == 0)      { X = X0; W = W0; bias = bi0; out = out0; K = 4000; do_sm = true; }
  else if (blockIdx.y == 1) { X = X1; W = W1; bias = bi1; out = out1; K = 4000; do_sm = true; }
  else                      { X = X2; W = W2; bias = bi2; out = out2; K = 1024; do_sm = false; }
  __shared__ float xs[4000];
  __shared__ float red[28][36];
  __shared__ float vals[36];
  __shared__ float mxv, smv;
  int b = blockIdx.x, tid = threadIdx.x;
  for (int i = tid; i < K; i += 256) xs[i] = X[(size_t)b * K + i];
  __syncthreads();
  if (tid < 252) {
    int c4 = tid % 9, g = tid / 9;
    const float4* W4 = (const float4*)W;
    float4 s = make_float4(0.f, 0.f, 0.f, 0.f);
    for (int k = g; k < K; k += 28) fma4(s, xs[k], W4[k * 9 + c4]);
    red[g][c4 * 4 + 0] = s.x; red[g][c4 * 4 + 1] = s.y;
    red[g][c4 * 4 + 2] = s.z; red[g][c4 * 4 + 3] = s.w;
  }
  __syncthreads();
  if (tid < 36) {
    float s = bias[tid];
    for (int g = 0; g < 28; ++g) s += red[g][tid];
    vals[tid] = s;
  }
  __syncthreads();
  if (do_sm) {
    if (tid == 0) {
      float m = -1e30f;
      for (int j = 0; j < 36; ++j) m = fmaxf(m, vals[j]);
      float e = 0.f;
      for (int j = 0; j < 36; ++j) e += expf(vals[j] - m);
      mxv = m; smv = e;
    }
    __syncthreads();
    if (tid < 36) out[b * 36 + tid] = expf(vals[tid] - mxv) / smv;
  } else {
    if (tid < 36) out[b * 36 + tid] = vals[tid];
  }
}

// ---------------- attention + CLIP loss + cell_cat (single block) ----------
__global__ __launch_bounds__(256) void head_kernel(
    const float* __restrict__ rna1, const float* __restrict__ cnv1,
    const float* __restrict__ pic1r, const float* __restrict__ aw1,
    const float* __restrict__ ab1, const float* __restrict__ aw2,
    const float* __restrict__ scale_p, float* __restrict__ cell_cat,
    float* __restrict__ dout) {
  __shared__ float z[2][32][36];
  __shared__ float pic1n[32][36];
  __shared__ float celln[32][36];
  __shared__ float fea[32][32];
  __shared__ float wvp[64];
  __shared__ float beta0, beta1;
  __shared__ float rowl[32], coll[32];
  int tid = threadIdx.x;
  for (int i = tid; i < 1152; i += 256) {
    int b = i / 36, k = i - (i / 36) * 36;
    z[0][b][k] = rna1[i];
    z[1][b][k] = cnv1[i];
    pic1n[b][k] = pic1r[i];
  }
  __syncthreads();
  {
    int p = tid >> 2, sub = tid & 3;
    int b = p >> 1, v = p & 1;
    float s = 0.f;
    for (int h = sub; h < 128; h += 4) {
      float a = ab1[h];
      for (int k = 0; k < 36; ++k) a += z[v][b][k] * aw1[k * 128 + h];
      s += tanhf(a) * aw2[h];
    }
    s += __shfl_down(s, 1, 64);
    s += __shfl_down(s, 2, 64);
    if (sub == 0) wvp[p] = s;
  }
  __syncthreads();
  if (tid == 0) {
    float w0 = 0.f, w1 = 0.f;
    for (int b = 0; b < 32; ++b) { w0 += wvp[b * 2]; w1 += wvp[b * 2 + 1]; }
    w0 /= 32.f; w1 /= 32.f;
    float m = fmaxf(w0, w1);
    float e0 = expf(w0 - m), e1 = expf(w1 - m);
    beta0 = e0 / (e0 + e1); beta1 = e1 / (e0 + e1);
  }
  __syncthreads();
  for (int i = tid; i < 1152; i += 256) {
    int b = i / 36, k = i - (i / 36) * 36;
    celln[b][k] = beta0 * z[0][b][k] + beta1 * z[1][b][k];
  }
  __syncthreads();
  if (tid < 32) {
    float s = 0.f;
    for (int k = 0; k < 36; ++k) { float x = pic1n[tid][k]; s += x * x; }
    float inv = 1.f / sqrtf(s);
    for (int k = 0; k < 36; ++k) pic1n[tid][k] *= inv;
  } else if (tid < 64) {
    int b = tid - 32;
    float s = 0.f;
    for (int k = 0; k < 36; ++k) { float x = celln[b][k]; s += x * x; }
    float inv = 1.f / sqrtf(s);
    for (int k = 0; k < 36; ++k) celln[b][k] *= inv;
  }
  __syncthreads();
  for (int i = tid; i < 1152; i += 256) {
    int b = i / 36, k = i - (i / 36) * 36;
    cell_cat[b * 72 + k] = celln[b][k];
    cell_cat[b * 72 + 36 + k] = pic1n[b][k];
  }
  float sc = *scale_p;
  for (int t = tid; t < 1024; t += 256) {
    int i = t >> 5, j = t & 31;
    float s = 0.f;
    for (int k = 0; k < 36; ++k) s += pic1n[i][k] * celln[j][k];
    fea[i][j] = sc * s;
  }
  __syncthreads();
  if (tid < 32) {
    float m = -1e30f;
    for (int j = 0; j < 32; ++j) m = fmaxf(m, fea[tid][j]);
    float e = 0.f;
    for (int j = 0; j < 32; ++j) e += expf(fea[tid][j] - m);
    rowl[tid] = (logf(e) + m) - fea[tid][tid];
  } else if (tid < 64) {
    int j = tid - 32;
    float m = -1e30f;
    for (int i = 0; i < 32; ++i) m = fmaxf(m, fea[i][j]);
    float e = 0.f;
    for (int i = 0; i < 32; ++i) e += expf(fea[i][j] - m);
    coll[j] = (logf(e) + m) - fea[j][j];
  }
  __syncthreads();
  if (tid == 0) {
    float s1 = 0.f, s2 = 0.f;
    for (int i = 0; i < 32; ++i) { s1 += rowl[i]; s2 += coll[i]; }
    dout[1] = 0.5f * (s1 / 32.f + s2 / 32.f);
  }
}

// ---------------- pair head + per-block CE partial sums --------------------
__global__ __launch_bounds__(256) void pair_kernel(
    const float* __restrict__ cell_cat, const float* __restrict__ drugfea,
    const int* __restrict__ idx, const int* __restrict__ target,
    const float* __restrict__ w1, const float* __restrict__ b1,
    const float* __restrict__ w2, const float* __restrict__ b2,
    float* __restrict__ bp_out, float* __restrict__ tgt_out,
    float* __restrict__ blocksums) {
  __shared__ float w1s[144][36];
  __shared__ float ccs[32][73];
  __shared__ float dfs[128][73];
  __shared__ float w2s[72], b2s[2];
  __shared__ float lsum[256];
  int tid = threadIdx.x;
  {
    float4* dst = (float4*)&w1s[0][0];
    const float4* src = (const float4*)w1;
    for (int i = tid; i < 1296; i += 256) dst[i] = src[i];
  }
  for (int i = tid; i < 2304; i += 256) ccs[i / 72][i % 72] = cell_cat[i];
  for (int i = tid; i < 9216; i += 256) dfs[i / 72][i % 72] = drugfea[i];
  if (tid < 72) w2s[tid] = w2[tid];
  if (tid < 2) b2s[tid] = b2[tid];
  __syncthreads();
  int p = blockIdx.x * 256 + tid;
  int ci = idx[p * 2], dj = idx[p * 2 + 1];
  float4 h4[9];
  {
    const float4* bb = (const float4*)b1;
#pragma unroll
    for (int q = 0; q < 9; ++q) h4[q] = bb[q];
  }
  for (int k = 0; k < 72; ++k) {
    float x = ccs[ci][k];
    const float4* wr = (const float4*)&w1s[k][0];
#pragma unroll
    for (int q = 0; q < 9; ++q) fma4(h4[q], x, wr[q]);
  }
  for (int k = 0; k < 72; ++k) {
    float x = dfs[dj][k];
    const float4* wr = (const float4*)&w1s[72 + k][0];
#pragma unroll
    for (int q = 0; q < 9; ++q) fma4(h4[q], x, wr[q]);
  }
  float l0 = b2s[0], l1 = b2s[1];
#pragma unroll
  for (int q = 0; q < 9; ++q) {
    float hv;
    hv = fmaxf(h4[q].x, 0.f); l0 += hv * w2s[(q * 4 + 0) * 2]; l1 += hv * w2s[(q * 4 + 0) * 2 + 1];
    hv = fmaxf(h4[q].y, 0.f); l0 += hv * w2s[(q * 4 + 1) * 2]; l1 += hv * w2s[(q * 4 + 1) * 2 + 1];
    hv = fmaxf(h4[q].z, 0.f); l0 += hv * w2s[(q * 4 + 2) * 2]; l1 += hv * w2s[(q * 4 + 2) * 2 + 1];
    hv = fmaxf(h4[q].w, 0.f); l0 += hv * w2s[(q * 4 + 3) * 2]; l1 += hv * w2s[(q * 4 + 3) * 2 + 1];
  }
  float m = fmaxf(l0, l1);
  float e0 = expf(l0 - m), e1 = expf(l1 - m);
  float inv = 1.f / (e0 + e1);
  float p0 = e0 * inv, p1 = e1 * inv;
  bp_out[p * 2] = p0;
  bp_out[p * 2 + 1] = p1;
  int t = target[p];
  float mm = fmaxf(p0, p1);
  float lse = logf(expf(p0 - mm) + expf(p1 - mm)) + mm;
  float chosen = t ? p1 : p0;
  lsum[tid] = lse - chosen;
  tgt_out[p] = (float)t;
  __syncthreads();
  for (int s = 128; s > 0; s >>= 1) {
    if (tid < s) lsum[tid] += lsum[tid + s];
    __syncthreads();
  }
  if (tid == 0) blocksums[blockIdx.x] = lsum[0];
}

__global__ void final_kernel(const float* __restrict__ blocksums, float* __restrict__ dout) {
  if (threadIdx.x == 0 && blockIdx.x == 0) {
    float s = 0.f;
    for (int i = 0; i < 16; ++i) s += blocksums[i];
    dout[0] = s / 4096.f;
  }
}

extern "C" void kernel_launch(void* const* d_in, const int* in_sizes, int n_in,
                              void* d_out, int out_size, void* d_ws, size_t ws_size,
                              hipStream_t stream) {
  (void)in_sizes; (void)n_in; (void)out_size; (void)ws_size;
  const float* pic        = (const float*)d_in[0];
  const float* rna        = (const float*)d_in[1];
  const float* cnv        = (const float*)d_in[2];
  const float* drug_fea   = (const float*)d_in[3];
  const float* drug_adj   = (const float*)d_in[4];
  const int*   index_list = (const int*)d_in[5];
  const int*   target     = (const int*)d_in[6];
  const float* logit_scale= (const float*)d_in[7];
  const float* conv_w     = (const float*)d_in[8];
  const float* conv_b     = (const float*)d_in[9];
  const float* fc1_w      = (const float*)d_in[10];
  const float* fc1_b      = (const float*)d_in[11];
  const float* fc2_w      = (const float*)d_in[12];
  const float* fc2_b      = (const float*)d_in[13];
  const float* m1w1       = (const float*)d_in[14];
  const float* m1b1       = (const float*)d_in[15];
  const float* m1w2       = (const float*)d_in[16];
  const float* m1b2       = (const float*)d_in[17];
  const float* m2w1       = (const float*)d_in[18];
  const float* m2b1       = (const float*)d_in[19];
  const float* m2w2       = (const float*)d_in[20];
  const float* m2b2       = (const float*)d_in[21];
  const float* aw1        = (const float*)d_in[22];
  const float* ab1        = (const float*)d_in[23];
  const float* aw2        = (const float*)d_in[24];
  const float* ew1        = (const float*)d_in[25];
  const float* eb1        = (const float*)d_in[26];
  const float* ew2        = (const float*)d_in[27];
  const float* eb2        = (const float*)d_in[28];
  const float* gw         = (const float*)d_in[29];
  const float* gw2        = (const float*)d_in[30];

  float* ws = (float*)d_ws;
  float* pooled  = ws;                   // 16,777,216 f
  float* pfc1    = ws + 16777216;        // 16,777,216 f (512*32*1024)
  float* p2fc1   = ws + 33554432;        //    131,072 f (4*32*1024)
  float* pm1     = ws + 33685504;        //  8,064,000 f (63*32*4000)
  float* pm2     = ws + 41749504;        //  8,064,000 f
  float* fcact   = ws + 49813504;        //     32,768 f
  float* h1      = ws + 49846272;        //    128,000 f
  float* h2      = ws + 49974272;        //    128,000 f
  float* rna1    = ws + 50102272;        //      1,152 f
  float* cnv1    = ws + 50103424;
  float* pic1r   = ws + 50104576;
  float* wcb     = ws + 50105728;        //      5,400 f
  float* drugf   = ws + 50111128;        //      9,216 f
  float* cellcat = ws + 50120344;        //      2,304 f
  float* bsums   = ws + 50122648;        //         16 f

  float* out = (float*)d_out;

  // K1: conv (4096) + wc (22)
  k1_conv_wc_kernel<<<4118, 256, 0, stream>>>(pic, conv_w, conv_b, pooled,
                                              gw, gw2, wcb);
  // K2: fc1 GEMM (512, chunk 1024) + mlp GEMMs (504); 4 cols/thread (r10)
  gemm_all_kernel<<<1016, 256, 0, stream>>>(pooled, fc1_w, pfc1,
                                            rna, m1w1, pm1, cnv, m2w1, pm2);
  // K3: fc1 reduce stage1 (128) || mlp reduces (250), float4
  k3_reduce_kernel<<<378, 256, 0, stream>>>(pfc1, p2fc1,
                                            pm1, m1b1, h1, pm2, m2b1, h2);
  // K4: fc1 reduce stage2 (32) || drug GCN (128)
  k4_s2_gcn_kernel<<<160, 256, 0, stream>>>(p2fc1, fc1_b, fcact,
                                            drug_fea, drug_adj, wcb, drugf);
  // K5: the three 36-col linears (+softmax)
  {
    dim3 g(32, 3);
    lin36_all_kernel<<<g, 256, 0, stream>>>(h1, m1w2, m1b2, rna1,
                                            h2, m2w2, m2b2, cnv1,
                                            fcact, fc2_w, fc2_b, pic1r);
  }
  // K6: attention + CLIP loss
  head_kernel<<<1, 256, 0, stream>>>(rna1, cnv1, pic1r, aw1, ab1, aw2,
                                     logit_scale, cellcat, out);
  // K7: pair prediction head
  pair_kernel<<<16, 256, 0, stream>>>(cellcat, drugf, index_list, target,
                                      ew1, eb1, ew2, eb2,
                                      out + 2, out + 2 + 8192, bsums);
  // K8: final CE mean
  final_kernel<<<1, 64, 0, stream>>>(bsums, out);
}